// Round 6
// baseline (478.663 us; speedup 1.0000x reference)
//
#include <hip/hip_runtime.h>

// WaveConv1d on MI355X — round 17: einsum_v11 (1KB w requests, H3 test).
//   out = x + idwt(E1(lo4)-lo4, E2(h4)-h4, 0, 0, 0)
// r16 post-mortem: v10 (barrier-free, LDS-free) was WORSE (185us, 1.0 TB/s) ->
// H2 falsified. Invariant across v5..v10: w staged/read in 256B wave-requests;
// best versions pin at 2.05 TB/s; effective latency under load back-computes
// to multiple us => memory path congested by request pattern, queueing hides
// every schedule change. H3: request SIZE is the lever. v11 re-tiles k to 256
// so every w stage = 1KB contiguous gl16 (odd rows: -8B shift + 16B side-DMA
// for the 2 tail floats); x re-laid [c][b16][k528-pad] so x staging = 1KB gl16
// too. v8's proven 3-buffer counted-vmcnt pipeline (never drains mid-loop).
// Main: 1024 blocks (4/CU, 36KB LDS), tile [16b][4o][256k], acc[4][4][4].
// Tail k=[512,522): 512 extra blocks, fp32 gather, hidden under main.

#define NROWS 4096          // B*C
#define MODES 522

#define M1 4101
#define M2 2056
#define M3 1033
#define M4 522

typedef unsigned int  uint;
typedef unsigned short ushort;

__constant__ float c_dlo[12] = {
  -0.00107730108499558f,  0.004777257511010651f,  0.0005538422009938016f,
  -0.031582039318031156f, 0.02752286553001629f,   0.09750160558707936f,
  -0.12976686756709563f,  -0.22626469396516913f,  0.3152503517092432f,
   0.7511339080215775f,   0.4946238903983854f,    0.11154074335008017f };
__constant__ float c_dhi[12] = {
  -0.11154074335008017f,  0.4946238903983854f,   -0.7511339080215775f,
   0.3152503517092432f,   0.22626469396516913f,  -0.12976686756709563f,
  -0.09750160558707936f,  0.02752286553001629f,   0.031582039318031156f,
   0.0005538422009938016f,-0.004777257511010651f, -0.00107730108499558f };
// Analysis (time-reversed) filters
__constant__ float c_alo[12] = {
   0.11154074335008017f,  0.4946238903983854f,    0.7511339080215775f,
   0.3152503517092432f,  -0.22626469396516913f,  -0.12976686756709563f,
   0.09750160558707936f,  0.02752286553001629f,  -0.031582039318031156f,
   0.0005538422009938016f, 0.004777257511010651f, -0.00107730108499558f };
__constant__ float c_ahi[12] = {
  -0.00107730108499558f, -0.004777257511010651f,  0.0005538422009938016f,
   0.031582039318031156f, 0.02752286553001629f,  -0.09750160558707936f,
  -0.12976686756709563f,  0.22626469396516913f,   0.3152503517092432f,
  -0.7511339080215775f,   0.4946238903983854f,   -0.11154074335008017f };

__device__ __forceinline__ ushort f2bf(float f) {
    uint b = __float_as_uint(f);
    uint r = (b + 0x7fffu + ((b >> 16) & 1u)) >> 16;
    return (ushort)r;
}

// async DMA global->LDS. LDS dest: wave-uniform base, lane l writes base+l*sz.
// Global src is per-lane. size must be a literal (4 or 16).
__device__ __forceinline__ void gl16(const void* g, void* l) {
    __builtin_amdgcn_global_load_lds(
        (const __attribute__((address_space(1))) void*)g,
        (__attribute__((address_space(3))) void*)l, 16, 0, 0);
}
__device__ __forceinline__ void gl4(const void* g, void* l) {
    __builtin_amdgcn_global_load_lds(
        (const __attribute__((address_space(1))) void*)g,
        (__attribute__((address_space(3))) void*)l, 4, 0, 0);
}

// One lo-only analysis level LDS->LDS, interior fast path (no reflect).
__device__ __forceinline__
void dwt_lo_lds(const float* __restrict__ src, int n, int m,
                float* __restrict__ dst, int tid)
{
    int jhi = (n - 2) >> 1;
    for (int j = tid; j < m; j += 256) {
        float a = 0.f;
        if (j >= 5 && j <= jhi) {
            const float* s = src + 2 * j - 10;
#pragma unroll
            for (int t = 0; t < 12; ++t) a += s[t] * c_alo[t];
        } else {
            int base = 2 * j - 10;
#pragma unroll
            for (int t = 0; t < 12; ++t) {
                int u = base + t;
                u = (u < 0) ? (-1 - u) : u;
                u = (u >= n) ? (2 * n - 1 - u) : u;
                a += src[u] * c_alo[t];
            }
        }
        dst[j] = a;
    }
}

// Fused forward DWT, lo-chain only: x -> (lo4, h4). One block per row.
__global__ __launch_bounds__(256)
void dwt_fused2(const float* __restrict__ x,
                float* __restrict__ lo4g, float* __restrict__ h4g)
{
    __shared__ float X[8192];
    __shared__ float LA[4104];
    int row = blockIdx.x, tid = threadIdx.x;

    const float4* xr = (const float4*)(x + (size_t)row * 8192);
    float4* Xv = (float4*)X;
#pragma unroll
    for (int i = 0; i < 8; ++i) Xv[tid + 256 * i] = xr[tid + 256 * i];
    __syncthreads();

    dwt_lo_lds(X,  8192, M1, LA, tid);
    __syncthreads();
    dwt_lo_lds(LA, M1,   M2, X,  tid);
    __syncthreads();
    dwt_lo_lds(X,  M2,   M3, LA, tid);
    __syncthreads();

    float* lo4r = lo4g + (size_t)row * M4;
    float* h4r  = h4g  + (size_t)row * M4;
    int jhi = (M3 - 2) >> 1;
    for (int j = tid; j < M4; j += 256) {
        float alo = 0.f, ahi = 0.f;
        if (j >= 5 && j <= jhi) {
            const float* s = LA + 2 * j - 10;
#pragma unroll
            for (int t = 0; t < 12; ++t) {
                float v = s[t];
                alo += v * c_alo[t]; ahi += v * c_ahi[t];
            }
        } else {
            int base = 2 * j - 10;
#pragma unroll
            for (int t = 0; t < 12; ++t) {
                int u = base + t;
                u = (u < 0) ? (-1 - u) : u;
                u = (u >= M3) ? (2 * M3 - 1 - u) : u;
                float v = LA[u];
                alo += v * c_alo[t]; ahi += v * c_ahi[t];
            }
        }
        lo4r[j] = alo; h4r[j] = ahi;
    }
}

// xpose4: [b][c][k] fp32 -> bf16 xT [c][b16][528] (row-padded to 1056B so
// every gl16 lane address in einsum_v11 is 16B-aligned; k>=522 pad unread).
// One block per (c, tensor). ALSO zero-fills dlo/dh for atomicAdd accum.
__global__ __launch_bounds__(256)
void xpose4(const float* __restrict__ lo4, const float* __restrict__ h4,
            ushort* __restrict__ xlT, ushort* __restrict__ xhT,
            float* __restrict__ dzero)
{
    __shared__ float L[16][528];
    int c = blockIdx.x;
    const float* src = blockIdx.y ? h4 : lo4;
    ushort*      dst = blockIdx.y ? xhT : xlT;
    int t = threadIdx.x;

    // zero dlo+dh: 2*SZ floats over 512 blocks x 256 thr
    {
        const size_t nz = ((size_t)2 * NROWS * M4) / 4;
        size_t gid = ((size_t)blockIdx.y * gridDim.x + blockIdx.x) * 256 + t;
        float4 z4 = make_float4(0.f, 0.f, 0.f, 0.f);
        float4* zp = (float4*)dzero;
        for (size_t i = gid; i < nz; i += (size_t)512 * 256) zp[i] = z4;
    }

#pragma unroll
    for (int b = 0; b < 16; ++b)
        for (int k = t; k < MODES; k += 256)
            L[b][k] = src[((size_t)b * 256 + c) * MODES + k];
    __syncthreads();

#pragma unroll
    for (int b = 0; b < 16; ++b)
        for (int k = t; k < MODES; k += 256)
            dst[((size_t)c * 16 + b) * 528 + k] = f2bf(L[b][k]);
}

// Delta-IDWT: A = dlo-lo4, Hs = dh-h4; lvl4 full -> lvl3,2,1 lo-only -> +x.
__global__ __launch_bounds__(256)
void idwt_delta2(const float* __restrict__ dlo, const float* __restrict__ dh,
                 const float* __restrict__ lo4, const float* __restrict__ h4,
                 const float* __restrict__ x,   float* __restrict__ out)
{
    __shared__ float A[2056];
    __shared__ float B[4104];
    __shared__ float Hs[528];
    int row = blockIdx.x, tid = threadIdx.x;

    for (int i = tid; i < M4; i += 256) {
        size_t idx = (size_t)row * M4 + i;
        A[i]  = dlo[idx] - lo4[idx];
        Hs[i] = dh[idx]  - h4[idx];
    }
    __syncthreads();

    for (int jj = tid; jj < M4 - 5; jj += 256) {
        float e = 0.f, od = 0.f;
#pragma unroll
        for (int s = 0; s < 6; ++s) {
            float xv = A[jj + s], hv = Hs[jj + s];
            e  += xv * c_dlo[2*s+1] + hv * c_dhi[2*s+1];
            od += xv * c_dlo[2*s]   + hv * c_dhi[2*s];
        }
        B[2*jj] = e; B[2*jj+1] = od;
    }
    __syncthreads();

    for (int jj = tid; jj < M3 - 5; jj += 256) {
        float e = 0.f, od = 0.f;
#pragma unroll
        for (int s = 0; s < 6; ++s) {
            float xv = B[jj + s];
            e  += xv * c_dlo[2*s+1];
            od += xv * c_dlo[2*s];
        }
        A[2*jj] = e; A[2*jj+1] = od;
    }
    __syncthreads();

    for (int jj = tid; jj < M2 - 5; jj += 256) {
        float e = 0.f, od = 0.f;
#pragma unroll
        for (int s = 0; s < 6; ++s) {
            float xv = A[jj + s];
            e  += xv * c_dlo[2*s+1];
            od += xv * c_dlo[2*s];
        }
        B[2*jj] = e; B[2*jj+1] = od;
    }
    __syncthreads();

    const float2* x2 = (const float2*)(x + (size_t)row * 8192);
    float2* o2 = (float2*)(out + (size_t)row * 8192);
    for (int jj = tid; jj < M1 - 5; jj += 256) {
        float e = 0.f, od = 0.f;
#pragma unroll
        for (int s = 0; s < 6; ++s) {
            float xv = B[jj + s];
            e  += xv * c_dlo[2*s+1];
            od += xv * c_dlo[2*s];
        }
        float2 xv2 = x2[jj];
        o2[jj] = make_float2(xv2.x + e, xv2.y + od);
    }
}

// Dual einsum v11. Main blocks (bid<1024): tile [16b][4o][256k], 64 i.
//   decode: iq=bid&3, kh=(bid>>2)&1, og=(bid>>3)&63, e=bid>>9
//   (the 64 og-siblings sharing an x-slice have equal bid%8 -> same XCD).
//   Staging per i (13 DMA/block, all wave-uniform LDS dests):
//     x: wave wv -> 2x gl16 (1KB each) from xT[c][b16][528pad], rows 4wv..4wv+3
//     w: wave wv -> 1x gl16 (1KB) row (i, o+wv) k-half kh; odd rows start -8B
//        (16B alignment), missing k-rel 254,255 staged via one gl4 (wave0,
//        lanes 0-3) into W2.
//   Pipeline: 3 LDS buffers, STAGE(ch+2) -> compute(ch) ->
//     "s_waitcnt vmcnt(3|4) lgkmcnt(0); s_barrier" (counted, never drains
//     mid-loop; wave0 has 4 DMAs/chunk due to the gl4).
//   Compute per thread per i: 4x uint2 LDS x-reads (b=4wv+bb), per j: w float4
//   (even) / 2x float2 (odd, lane63 tail from W2), 64 FMA. acc[4][4][4].
//   Flush: atomicAdd (4 iq parts), k<512 only.
// Tail blocks (bid>=1024): k=[512,522): tb=bid-1024, e=tb>>8, o=tb&255;
//   thread (b=t&15, kt=t>>4<10) gathers over 256 i in fp32; direct store.
__global__ __launch_bounds__(256)
void einsum_v11(const ushort* __restrict__ xlT, const ushort* __restrict__ xhT,
                const float* __restrict__ w1,   const float* __restrict__ w2,
                const float* __restrict__ lo4,  const float* __restrict__ h4,
                float* __restrict__ dlo, float* __restrict__ dh)
{
    __shared__ __align__(16) ushort Xl[3][4096];   // [buf][b16*256k] 8KB/buf
    __shared__ __align__(16) float  Wl[3][1024];   // [buf][j4*256k]  4KB/buf
    __shared__ __align__(16) float  W2[3][4];      // odd-row k-rel 254,255

    int bid = blockIdx.x;
    if (bid < 1024) {
        int iq = bid & 3;
        int kh = (bid >> 2) & 1;
        int og = (bid >> 3) & 63;
        int e  = bid >> 9;

        const ushort* xT = e ? xhT : xlT;
        const float*  w  = e ? w2  : w1;
        float* outp      = e ? dh  : dlo;

        int lane = threadIdx.x & 63;
        int wv   = threadIdx.x >> 6;
        int o    = og * 4;
        int i0   = iq * 64;
        int kb   = kh * 256;

        // ---- per-lane global bases ----
        // x rows (row stride 1056 B, c stride 16896 B)
        const char* xg0 = (const char*)xT
            + (size_t)(i0 * 16 + 4 * wv + (lane >> 5)) * 1056
            + (size_t)kb * 2 + (size_t)(lane & 31) * 16;
        const size_t XSTR = 16896;                 // bytes per i
        // w row (i, o+wv), k-half kh; odd rows shifted -8B for 16B alignment
        const char* wg = (const char*)w
            + (size_t)(i0 * 256 + o + wv) * 2088 + (size_t)kh * 1024
            + (size_t)lane * 16 - ((wv & 1) ? 8 : 0);
        const size_t WSTR = 534528;                // bytes per i (256*2088)
        // W2 source (wave0 lanes 0..3): rows o+1,o+3, k = kb+254,kb+255
        const char* w2g = (const char*)w
            + (size_t)(i0 * 256 + o + 1 + 2 * (lane >> 1)) * 2088
            + (size_t)(kb + 254 + (lane & 1)) * 4;

        float acc[4][4][4];
#pragma unroll
        for (int bb = 0; bb < 4; ++bb)
#pragma unroll
            for (int j = 0; j < 4; ++j)
#pragma unroll
                for (int kk = 0; kk < 4; ++kk) acc[bb][j][kk] = 0.f;

#define STAGE(bi, ci) do {                                                    \
        const char* xa_ = xg0 + (size_t)(ci) * XSTR;                          \
        gl16(xa_,        &Xl[bi][wv * 1024]);                                 \
        gl16(xa_ + 2112, &Xl[bi][wv * 1024 + 512]);                           \
        gl16(wg + (size_t)(ci) * WSTR, &Wl[bi][wv * 256]);                    \
        if (wv == 0 && lane < 4)                                              \
            gl4(w2g + (size_t)(ci) * WSTR, &W2[bi][0]);                       \
    } while (0)

#define WAITP do {                                                            \
        if (wv == 0)                                                          \
            asm volatile("s_waitcnt vmcnt(4) lgkmcnt(0)\n\ts_barrier"         \
                         ::: "memory");                                       \
        else                                                                  \
            asm volatile("s_waitcnt vmcnt(3) lgkmcnt(0)\n\ts_barrier"         \
                         ::: "memory");                                       \
    } while (0)

        // ---- prologue: chunks 0,1 in flight; wait chunk 0 ----
        STAGE(0, 0);
        STAGE(1, 1);
        WAITP;

        int cur = 0;
        for (int ch = 0; ch < 64; ++ch) {
            int nb = cur + 2; if (nb >= 3) nb -= 3;
            if (ch < 62) STAGE(nb, ch + 2);

            // ---- compute chunk ch from buf cur ----
            {
                const ushort* Xc = Xl[cur];
                const float*  Wc = Wl[cur];
                // x: b = 4wv+bb, k = 4lane..4lane+3
                float xf[4][4];
#pragma unroll
                for (int bb = 0; bb < 4; ++bb) {
                    uint2 xp = *(const uint2*)(Xc + (4 * wv + bb) * 256 + lane * 4);
                    xf[bb][0] = __uint_as_float(xp.x << 16);
                    xf[bb][1] = __uint_as_float(xp.x & 0xffff0000u);
                    xf[bb][2] = __uint_as_float(xp.y << 16);
                    xf[bb][3] = __uint_as_float(xp.y & 0xffff0000u);
                }
#pragma unroll
                for (int j = 0; j < 4; ++j) {
                    float wk0, wk1, wk2, wk3;
                    if ((j & 1) == 0) {
                        float4 w4 = *(const float4*)(Wc + j * 256 + lane * 4);
                        wk0 = w4.x; wk1 = w4.y; wk2 = w4.z; wk3 = w4.w;
                    } else {
                        float2 wa = *(const float2*)(Wc + j * 256 + lane * 4 + 2);
                        float2 wb;
                        if (lane < 63)
                            wb = *(const float2*)(Wc + j * 256 + lane * 4 + 4);
                        else
                            wb = *(const float2*)(&W2[cur][(j >> 1) * 2]);
                        wk0 = wa.x; wk1 = wa.y; wk2 = wb.x; wk3 = wb.y;
                    }
#pragma unroll
                    for (int bb = 0; bb < 4; ++bb) {
                        acc[bb][j][0] += xf[bb][0] * wk0;
                        acc[bb][j][1] += xf[bb][1] * wk1;
                        acc[bb][j][2] += xf[bb][2] * wk2;
                        acc[bb][j][3] += xf[bb][3] * wk3;
                    }
                }
            }

            if (ch < 62)       WAITP;
            else if (ch == 62)
                asm volatile("s_waitcnt vmcnt(0) lgkmcnt(0)\n\ts_barrier"
                             ::: "memory");

            cur = cur + 1; if (cur >= 3) cur -= 3;
        }
#undef STAGE
#undef WAITP

        // ---- flush: atomicAdd (4 iq parts per element) ----
#pragma unroll
        for (int bb = 0; bb < 4; ++bb) {
            int b = 4 * wv + bb;
#pragma unroll
            for (int j = 0; j < 4; ++j) {
                float* op = outp + ((size_t)(b * 256 + o + j)) * MODES
                                 + kb + 4 * lane;
#pragma unroll
                for (int kk = 0; kk < 4; ++kk)
                    atomicAdd(op + kk, acc[bb][j][kk]);
            }
        }
    } else {
        // ---- tail: k in [512,522) ----
        int tb = bid - 1024;
        int e  = tb >> 8;
        int o  = tb & 255;
        const float* w  = e ? w2 : w1;
        const float* xs = e ? h4 : lo4;
        float* outp     = e ? dh : dlo;
        int t = threadIdx.x;
        int b = t & 15, kt = t >> 4;
        if (kt < 10) {
            const float* wp = w  + (size_t)o * MODES + 512 + kt;
            const float* xp = xs + (size_t)b * 256 * MODES + 512 + kt;
            float a = 0.f;
#pragma unroll 8
            for (int i = 0; i < 256; ++i)
                a += xp[(size_t)i * MODES] * wp[(size_t)i * 256 * MODES];
            outp[((size_t)(b * 256 + o)) * MODES + 512 + kt] = a;
        }
    }
}

extern "C" void kernel_launch(void* const* d_in, const int* in_sizes, int n_in,
                              void* d_out, int out_size, void* d_ws, size_t ws_size,
                              hipStream_t stream)
{
    const float* x  = (const float*)d_in[0];
    const float* w1 = (const float*)d_in[1];
    const float* w2 = (const float*)d_in[2];
    float* out = (float*)d_out;
    float* ws  = (float*)d_ws;

    const size_t SZ = (size_t)NROWS * M4;   // 2,138,112
    float* lo4 = ws;
    float* h4  = lo4 + SZ;
    float* dlo = h4  + SZ;
    float* dh  = dlo + SZ;                   // dlo,dh contiguous (zeroed together)
    ushort* xlT = (ushort*)(dh + SZ);        // 256*16*528 ushorts per tensor
    ushort* xhT = xlT + (size_t)256 * 16 * 528;

    dim3 blk(256);

    dwt_fused2<<<NROWS, blk, 0, stream>>>(x, lo4, h4);
    xpose4<<<dim3(256, 2), blk, 0, stream>>>(lo4, h4, xlT, xhT, dlo);
    einsum_v11<<<1536, blk, 0, stream>>>(xlT, xhT, w1, w2, lo4, h4, dlo, dh);
    idwt_delta2<<<NROWS, blk, 0, stream>>>(dlo, dh, lo4, h4, x, out);
}

// Round 7
// 212.868 us; speedup vs baseline: 2.2486x; 2.2486x over previous
//
#include <hip/hip_runtime.h>

// WaveConv1d on MI355X — round 18: consolidate.
//   out = x + idwt(E1(lo4)-lo4, E2(h4)-h4, 0, 0, 0)
// r17 post-mortem: six einsum structures (113->341us) never beat v5's 113.6us;
// three bottleneck theories falsified. Declare einsum at its empirical local
// floor, revert to v5 verbatim (plain stores, no zeroing, no atomics), and
// recover the untouched 131us in the OTHER kernels:
//   1. xpose2 DELETED: dwt_fused2 emits bf16 xT[c][g][k][b4] scattered stores
//      directly from its level-4 registers (saves 34MB read + a launch).
//   2. dwt levels vectorized: thread computes an output PAIR from 7 float2
//      LDS reads (vs 24 scalar b32) — dwt was LDS-instruction bound.
//   3. idwt levels vectorized: pair-per-thread, float2 reads + float4 store;
//      final level reads x / writes out as float4.

#define NROWS 4096          // B*C
#define MODES 522

#define M1 4101
#define M2 2056
#define M3 1033
#define M4 522

typedef unsigned int  uint;
typedef unsigned short ushort;

__constant__ float c_dlo[12] = {
  -0.00107730108499558f,  0.004777257511010651f,  0.0005538422009938016f,
  -0.031582039318031156f, 0.02752286553001629f,   0.09750160558707936f,
  -0.12976686756709563f,  -0.22626469396516913f,  0.3152503517092432f,
   0.7511339080215775f,   0.4946238903983854f,    0.11154074335008017f };
__constant__ float c_dhi[12] = {
  -0.11154074335008017f,  0.4946238903983854f,   -0.7511339080215775f,
   0.3152503517092432f,   0.22626469396516913f,  -0.12976686756709563f,
  -0.09750160558707936f,  0.02752286553001629f,   0.031582039318031156f,
   0.0005538422009938016f,-0.004777257511010651f, -0.00107730108499558f };
// Analysis (time-reversed) filters
__constant__ float c_alo[12] = {
   0.11154074335008017f,  0.4946238903983854f,    0.7511339080215775f,
   0.3152503517092432f,  -0.22626469396516913f,  -0.12976686756709563f,
   0.09750160558707936f,  0.02752286553001629f,  -0.031582039318031156f,
   0.0005538422009938016f, 0.004777257511010651f, -0.00107730108499558f };
__constant__ float c_ahi[12] = {
  -0.00107730108499558f, -0.004777257511010651f,  0.0005538422009938016f,
   0.031582039318031156f, 0.02752286553001629f,  -0.09750160558707936f,
  -0.12976686756709563f,  0.22626469396516913f,   0.3152503517092432f,
  -0.7511339080215775f,   0.4946238903983854f,   -0.11154074335008017f };

__device__ __forceinline__ ushort f2bf(float f) {
    uint b = __float_as_uint(f);
    uint r = (b + 0x7fffu + ((b >> 16) & 1u)) >> 16;
    return (ushort)r;
}

// One lo-only analysis level LDS->LDS, PAIR-vectorized: thread computes
// outputs (j0, j0+1) from 7 float2 LDS reads (window src[2j0-10 .. 2j0+3]).
__device__ __forceinline__
void dwt_lo_pairs(const float* __restrict__ src, int n, int m,
                  float* __restrict__ dst, int tid)
{
    int jhi = (n - 2) >> 1;
    int npairs = (m + 1) >> 1;
    for (int jp = tid; jp < npairs; jp += 256) {
        int j0 = 2 * jp;
        if (j0 >= 6 && j0 + 1 <= jhi) {
            const float2* s2 = (const float2*)(src + 2 * j0 - 10);
            float2 p0 = s2[0], p1 = s2[1], p2 = s2[2], p3 = s2[3],
                   p4 = s2[4], p5 = s2[5], p6 = s2[6];
            float a0 =
                p0.x*c_alo[0] + p0.y*c_alo[1] + p1.x*c_alo[2] + p1.y*c_alo[3] +
                p2.x*c_alo[4] + p2.y*c_alo[5] + p3.x*c_alo[6] + p3.y*c_alo[7] +
                p4.x*c_alo[8] + p4.y*c_alo[9] + p5.x*c_alo[10]+ p5.y*c_alo[11];
            float a1 =
                p1.x*c_alo[0] + p1.y*c_alo[1] + p2.x*c_alo[2] + p2.y*c_alo[3] +
                p3.x*c_alo[4] + p3.y*c_alo[5] + p4.x*c_alo[6] + p4.y*c_alo[7] +
                p5.x*c_alo[8] + p5.y*c_alo[9] + p6.x*c_alo[10]+ p6.y*c_alo[11];
            *(float2*)&dst[j0] = make_float2(a0, a1);
        } else {
#pragma unroll
            for (int q = 0; q < 2; ++q) {
                int j = j0 + q;
                if (j < m) {
                    int base = 2 * j - 10;
                    float a = 0.f;
#pragma unroll
                    for (int t = 0; t < 12; ++t) {
                        int u = base + t;
                        u = (u < 0) ? (-1 - u) : u;
                        u = (u >= n) ? (2 * n - 1 - u) : u;
                        a += src[u] * c_alo[t];
                    }
                    dst[j] = a;
                }
            }
        }
    }
}

// Fused forward DWT, lo-chain only: x -> (lo4, h4) fp32 AND bf16 xT
// [c][g4][k][b4] scattered stores (replaces the old xpose2 kernel).
// One block per row; row = b*256 + c.
__global__ __launch_bounds__(256)
void dwt_fused3(const float* __restrict__ x,
                float* __restrict__ lo4g, float* __restrict__ h4g,
                ushort* __restrict__ xlT, ushort* __restrict__ xhT)
{
    __shared__ float X[8192];
    __shared__ float LA[4104];
    int row = blockIdx.x, tid = threadIdx.x;

    const float4* xr = (const float4*)(x + (size_t)row * 8192);
    float4* Xv = (float4*)X;
#pragma unroll
    for (int i = 0; i < 8; ++i) Xv[tid + 256 * i] = xr[tid + 256 * i];
    __syncthreads();

    dwt_lo_pairs(X,  8192, M1, LA, tid);
    __syncthreads();
    dwt_lo_pairs(LA, M1,   M2, X,  tid);
    __syncthreads();
    dwt_lo_pairs(X,  M2,   M3, LA, tid);
    __syncthreads();

    // level 4: dual filter, write lo4/h4 fp32 + xlT/xhT bf16 (scattered)
    float* lo4r = lo4g + (size_t)row * M4;
    float* h4r  = h4g  + (size_t)row * M4;
    int b  = row >> 8, c = row & 255;
    int cg = c * 4 + (b >> 2);
    int b4 = b & 3;
    int jhi = (M3 - 2) >> 1;            // 515
    for (int jp = tid; jp < 261; jp += 256) {
        int j0 = 2 * jp;                // j0+1 = 521 max, always a full pair
        float alo0, ahi0, alo1, ahi1;
        if (j0 >= 6 && j0 + 1 <= jhi) {
            const float2* s2 = (const float2*)(LA + 2 * j0 - 10);
            float2 p0 = s2[0], p1 = s2[1], p2 = s2[2], p3 = s2[3],
                   p4 = s2[4], p5 = s2[5], p6 = s2[6];
            alo0 =
                p0.x*c_alo[0] + p0.y*c_alo[1] + p1.x*c_alo[2] + p1.y*c_alo[3] +
                p2.x*c_alo[4] + p2.y*c_alo[5] + p3.x*c_alo[6] + p3.y*c_alo[7] +
                p4.x*c_alo[8] + p4.y*c_alo[9] + p5.x*c_alo[10]+ p5.y*c_alo[11];
            ahi0 =
                p0.x*c_ahi[0] + p0.y*c_ahi[1] + p1.x*c_ahi[2] + p1.y*c_ahi[3] +
                p2.x*c_ahi[4] + p2.y*c_ahi[5] + p3.x*c_ahi[6] + p3.y*c_ahi[7] +
                p4.x*c_ahi[8] + p4.y*c_ahi[9] + p5.x*c_ahi[10]+ p5.y*c_ahi[11];
            alo1 =
                p1.x*c_alo[0] + p1.y*c_alo[1] + p2.x*c_alo[2] + p2.y*c_alo[3] +
                p3.x*c_alo[4] + p3.y*c_alo[5] + p4.x*c_alo[6] + p4.y*c_alo[7] +
                p5.x*c_alo[8] + p5.y*c_alo[9] + p6.x*c_alo[10]+ p6.y*c_alo[11];
            ahi1 =
                p1.x*c_ahi[0] + p1.y*c_ahi[1] + p2.x*c_ahi[2] + p2.y*c_ahi[3] +
                p3.x*c_ahi[4] + p3.y*c_ahi[5] + p4.x*c_ahi[6] + p4.y*c_ahi[7] +
                p5.x*c_ahi[8] + p5.y*c_ahi[9] + p6.x*c_ahi[10]+ p6.y*c_ahi[11];
        } else {
            float r0[2];
#pragma unroll
            for (int q = 0; q < 2; ++q) {
                int base = 2 * (j0 + q) - 10;
                float al = 0.f, ah = 0.f;
#pragma unroll
                for (int t = 0; t < 12; ++t) {
                    int u = base + t;
                    u = (u < 0) ? (-1 - u) : u;
                    u = (u >= M3) ? (2 * M3 - 1 - u) : u;
                    float v = LA[u];
                    al += v * c_alo[t]; ah += v * c_ahi[t];
                }
                if (q == 0) { alo0 = al; ahi0 = ah; }
                else        { alo1 = al; ahi1 = ah; }
                r0[q] = al;
            }
            (void)r0;
        }
        *(float2*)&lo4r[j0] = make_float2(alo0, alo1);
        *(float2*)&h4r[j0]  = make_float2(ahi0, ahi1);
        size_t xi = ((size_t)cg * MODES + j0) * 4 + b4;
        xlT[xi]     = f2bf(alo0);
        xlT[xi + 4] = f2bf(alo1);
        xhT[xi]     = f2bf(ahi0);
        xhT[xi + 4] = f2bf(ahi1);
    }
}

// One synthesis (lo-only) level LDS->LDS, pair-vectorized:
// thread tp handles jj = 2tp, 2tp+1; reads S[jj..jj+6] as float2s,
// writes D[2jj..2jj+3] as one float4.
__device__ __forceinline__
void ilvl_lo(const float* __restrict__ S, float* __restrict__ D,
             int L, int tid)
{
    int npairs = (L + 1) >> 1;
    for (int tp = tid; tp < npairs; tp += 256) {
        int jj = 2 * tp;
        const float2* s2 = (const float2*)(S + jj);
        float2 q0 = s2[0], q1 = s2[1], q2 = s2[2];
        float e0 = q0.x*c_dlo[1] + q0.y*c_dlo[3] + q1.x*c_dlo[5]
                 + q1.y*c_dlo[7] + q2.x*c_dlo[9] + q2.y*c_dlo[11];
        float od0= q0.x*c_dlo[0] + q0.y*c_dlo[2] + q1.x*c_dlo[4]
                 + q1.y*c_dlo[6] + q2.x*c_dlo[8] + q2.y*c_dlo[10];
        if (jj + 1 < L) {
            float2 q3 = s2[3];
            float e1 = q0.y*c_dlo[1] + q1.x*c_dlo[3] + q1.y*c_dlo[5]
                     + q2.x*c_dlo[7] + q2.y*c_dlo[9] + q3.x*c_dlo[11];
            float od1= q0.y*c_dlo[0] + q1.x*c_dlo[2] + q1.y*c_dlo[4]
                     + q2.x*c_dlo[6] + q2.y*c_dlo[8] + q3.x*c_dlo[10];
            *(float4*)&D[2*jj] = make_float4(e0, od0, e1, od1);
        } else {
            D[2*jj] = e0; D[2*jj+1] = od0;
        }
    }
}

// Delta-IDWT: A = dlo-lo4, Hs = dh-h4; lvl4 full -> lvl3,2,1 lo-only -> +x.
// All levels pair-vectorized.
__global__ __launch_bounds__(256)
void idwt_delta3(const float* __restrict__ dlo, const float* __restrict__ dh,
                 const float* __restrict__ lo4, const float* __restrict__ h4,
                 const float* __restrict__ x,   float* __restrict__ out)
{
    __shared__ float A[2056];
    __shared__ float B[4104];
    __shared__ float Hs[528];
    int row = blockIdx.x, tid = threadIdx.x;

    {
        const float2* dl2 = (const float2*)(dlo + (size_t)row * M4);
        const float2* lo2 = (const float2*)(lo4 + (size_t)row * M4);
        const float2* dh2 = (const float2*)(dh  + (size_t)row * M4);
        const float2* h42 = (const float2*)(h4  + (size_t)row * M4);
        for (int tp = tid; tp < 261; tp += 256) {
            float2 a = dl2[tp], bvl = lo2[tp];
            float2 hdd = dh2[tp], hb = h42[tp];
            *(float2*)&A[2*tp]  = make_float2(a.x - bvl.x, a.y - bvl.y);
            *(float2*)&Hs[2*tp] = make_float2(hdd.x - hb.x, hdd.y - hb.y);
        }
    }
    __syncthreads();

    // level 4: dual input (A, Hs), L = M4-5 = 517
    {
        const int L = M4 - 5;
        int npairs = (L + 1) >> 1;   // 259
        for (int tp = tid; tp < npairs; tp += 256) {
            int jj = 2 * tp;
            const float2* a2 = (const float2*)(A + jj);
            const float2* h2 = (const float2*)(Hs + jj);
            float2 a0 = a2[0], a1 = a2[1], aq2 = a2[2];
            float2 h0 = h2[0], h1 = h2[1], hq2 = h2[2];
            float e0 = a0.x*c_dlo[1] + a0.y*c_dlo[3] + a1.x*c_dlo[5]
                     + a1.y*c_dlo[7] + aq2.x*c_dlo[9] + aq2.y*c_dlo[11]
                     + h0.x*c_dhi[1] + h0.y*c_dhi[3] + h1.x*c_dhi[5]
                     + h1.y*c_dhi[7] + hq2.x*c_dhi[9] + hq2.y*c_dhi[11];
            float od0= a0.x*c_dlo[0] + a0.y*c_dlo[2] + a1.x*c_dlo[4]
                     + a1.y*c_dlo[6] + aq2.x*c_dlo[8] + aq2.y*c_dlo[10]
                     + h0.x*c_dhi[0] + h0.y*c_dhi[2] + h1.x*c_dhi[4]
                     + h1.y*c_dhi[6] + hq2.x*c_dhi[8] + hq2.y*c_dhi[10];
            if (jj + 1 < L) {
                float2 a3 = a2[3], h3 = h2[3];
                float e1 = a0.y*c_dlo[1] + a1.x*c_dlo[3] + a1.y*c_dlo[5]
                         + aq2.x*c_dlo[7] + aq2.y*c_dlo[9] + a3.x*c_dlo[11]
                         + h0.y*c_dhi[1] + h1.x*c_dhi[3] + h1.y*c_dhi[5]
                         + hq2.x*c_dhi[7] + hq2.y*c_dhi[9] + h3.x*c_dhi[11];
                float od1= a0.y*c_dlo[0] + a1.x*c_dlo[2] + a1.y*c_dlo[4]
                         + aq2.x*c_dlo[6] + aq2.y*c_dlo[8] + a3.x*c_dlo[10]
                         + h0.y*c_dhi[0] + h1.x*c_dhi[2] + h1.y*c_dhi[4]
                         + hq2.x*c_dhi[6] + hq2.y*c_dhi[8] + h3.x*c_dhi[10];
                *(float4*)&B[2*jj] = make_float4(e0, od0, e1, od1);
            } else {
                B[2*jj] = e0; B[2*jj+1] = od0;
            }
        }
    }
    __syncthreads();

    ilvl_lo(B, A, M3 - 5, tid);      // -> A[0..2055]
    __syncthreads();
    ilvl_lo(A, B, M2 - 5, tid);      // -> B[0..4101]
    __syncthreads();

    // final level: L = M1-5 = 4096 (even -> always full pairs), fused +x.
    {
        const float4* x4 = (const float4*)(x + (size_t)row * 8192);
        float4* o4 = (float4*)(out + (size_t)row * 8192);
        for (int tp = tid; tp < 2048; tp += 256) {
            int jj = 2 * tp;
            const float2* s2 = (const float2*)(B + jj);
            float2 q0 = s2[0], q1 = s2[1], q2 = s2[2], q3 = s2[3];
            float e0 = q0.x*c_dlo[1] + q0.y*c_dlo[3] + q1.x*c_dlo[5]
                     + q1.y*c_dlo[7] + q2.x*c_dlo[9] + q2.y*c_dlo[11];
            float od0= q0.x*c_dlo[0] + q0.y*c_dlo[2] + q1.x*c_dlo[4]
                     + q1.y*c_dlo[6] + q2.x*c_dlo[8] + q2.y*c_dlo[10];
            float e1 = q0.y*c_dlo[1] + q1.x*c_dlo[3] + q1.y*c_dlo[5]
                     + q2.x*c_dlo[7] + q2.y*c_dlo[9] + q3.x*c_dlo[11];
            float od1= q0.y*c_dlo[0] + q1.x*c_dlo[2] + q1.y*c_dlo[4]
                     + q2.x*c_dlo[6] + q2.y*c_dlo[8] + q3.x*c_dlo[10];
            float4 xv = x4[tp];
            o4[tp] = make_float4(xv.x + e0, xv.y + od0, xv.z + e1, xv.w + od1);
        }
    }
}

// Dual einsum v5 (verbatim from the round-0 244.7us kernel, measured 113.6us):
// both operands through LDS double-buffers.
// dlo[b,o,k] = sum_i x[b,i,k]*w[i,o,k]   (subtract happens in idwt_delta3)
// Grid 1152: wg<576 -> (xlT,w1,dlo), else (xhT,w2,dh).
// Decode: u<512: kt=u&7 (XCD-pinned), oq=u>>3; else kt=8 -> kbase=MODES-64
// (k-overlap blocks write identical bits - benign).
// Chunk = 4 i; 64 chunks; per chunk/thread: 2 dwordx4 (x bf16) + 4 dword (w)
// staged loads; compute pure LDS: per ii {1 ds_read_b64 x, 4 ds_read_b32 w,
// 2 unpack, 16 FMA}. Wave wv owns b-quad g=wv; acc[4][4]; no reduce.
__global__ __launch_bounds__(256)
void einsum_v5(const ushort* __restrict__ xlT, const ushort* __restrict__ xhT,
               const float* __restrict__ w1,   const float* __restrict__ w2,
               float* __restrict__ dlo, float* __restrict__ dh)
{
    __shared__ ushort Xb[2][4096];   // [buf][ ((il*4+g)*64 + kk)*4 + b ]  16 KB
    __shared__ float  Wb[2][1024];   // [buf][ (il*4+j)*64 + kk ]           8 KB

    int wg = blockIdx.x;
    int e = (wg >= 576); if (e) wg -= 576;
    const ushort* xT = e ? xhT : xlT;
    const float*  w  = e ? w2  : w1;
    float* outp      = e ? dh  : dlo;

    int kt, oq;
    if (wg < 512) { kt = wg & 7; oq = wg >> 3; }
    else          { kt = 8;      oq = wg - 512; }
    int kbase = (kt < 8) ? kt * 64 : (MODES - 64);
    int lane = threadIdx.x & 63;
    int wv   = threadIdx.x >> 6;
    int o    = oq * 4;
    int t    = threadIdx.x;

    // staging decode (same for x and w): run = t>>4 -> (il = run>>2, sub = run&3)
    int run = t >> 4, piece = t & 15;
    int il = run >> 2, sub = run & 3;

    // x: run (il, g=sub): 512 B; piece = 32 B
    const ushort* xrunb = xT + (((size_t)il * 4 + sub) * MODES + kbase) * 4 + piece * 16;
    const size_t xistr = (size_t)4 * MODES * 4;           // ushorts per i
    // w: run (il, j=sub): 256 B; piece = 16 B
    const float* wrunb = w + ((size_t)il * 256 + o + sub) * MODES + kbase + piece * 4;
    const size_t wistr = (size_t)256 * MODES;             // floats per i

    float acc[4][4];
#pragma unroll
    for (int q = 0; q < 4; ++q)
#pragma unroll
        for (int j = 0; j < 4; ++j) acc[q][j] = 0.f;

    // ---- prologue: stage chunk 0 (i = 0..3) ----
    {
        uint4 v0 = *(const uint4*)(xrunb);
        uint4 v1 = *(const uint4*)(xrunb + 8);
        float f0 = wrunb[0], f1 = wrunb[1], f2 = wrunb[2], f3 = wrunb[3];
        uint4* xd = (uint4*)&Xb[0][t * 16];
        xd[0] = v0; xd[1] = v1;
        float4* wd = (float4*)&Wb[0][t * 4];
        *wd = make_float4(f0, f1, f2, f3);
    }
    __syncthreads();

    for (int ch = 0; ch < 64; ++ch) {
        int cur = ch & 1, nb = cur ^ 1;
        uint4 v0, v1; float f0, f1, f2, f3;
        if (ch < 63) {
            const ushort* xs = xrunb + (size_t)(ch + 1) * 4 * xistr;
            v0 = *(const uint4*)(xs);
            v1 = *(const uint4*)(xs + 8);
            const float* wsv = wrunb + (size_t)(ch + 1) * 4 * wistr;
            f0 = wsv[0]; f1 = wsv[1]; f2 = wsv[2]; f3 = wsv[3];
        }

        // compute chunk ch from buf cur
#pragma unroll
        for (int ii = 0; ii < 4; ++ii) {
            uint2 xp = *(const uint2*)&Xb[cur][(((ii * 4) + wv) * 64 + lane) * 4];
            float x0 = __uint_as_float(xp.x << 16);
            float x1 = __uint_as_float(xp.x & 0xffff0000u);
            float x2 = __uint_as_float(xp.y << 16);
            float x3 = __uint_as_float(xp.y & 0xffff0000u);
            float wr0 = Wb[cur][(ii * 4 + 0) * 64 + lane];
            float wr1 = Wb[cur][(ii * 4 + 1) * 64 + lane];
            float wr2 = Wb[cur][(ii * 4 + 2) * 64 + lane];
            float wr3 = Wb[cur][(ii * 4 + 3) * 64 + lane];
            acc[0][0] += x0 * wr0; acc[0][1] += x0 * wr1;
            acc[0][2] += x0 * wr2; acc[0][3] += x0 * wr3;
            acc[1][0] += x1 * wr0; acc[1][1] += x1 * wr1;
            acc[1][2] += x1 * wr2; acc[1][3] += x1 * wr3;
            acc[2][0] += x2 * wr0; acc[2][1] += x2 * wr1;
            acc[2][2] += x2 * wr2; acc[2][3] += x2 * wr3;
            acc[3][0] += x3 * wr0; acc[3][1] += x3 * wr1;
            acc[3][2] += x3 * wr2; acc[3][3] += x3 * wr3;
        }

        if (ch < 63) {
            uint4* xd = (uint4*)&Xb[nb][t * 16];
            xd[0] = v0; xd[1] = v1;
            float4* wd = (float4*)&Wb[nb][t * 4];
            *wd = make_float4(f0, f1, f2, f3);
        }
        __syncthreads();
    }

    // store raw sums (subtraction deferred to idwt_delta3)
#pragma unroll
    for (int q = 0; q < 4; ++q) {
        int b = 4 * wv + q;
#pragma unroll
        for (int j = 0; j < 4; ++j)
            outp[((size_t)b * 256 + o + j) * MODES + kbase + lane] = acc[q][j];
    }
}

extern "C" void kernel_launch(void* const* d_in, const int* in_sizes, int n_in,
                              void* d_out, int out_size, void* d_ws, size_t ws_size,
                              hipStream_t stream)
{
    const float* x  = (const float*)d_in[0];
    const float* w1 = (const float*)d_in[1];
    const float* w2 = (const float*)d_in[2];
    float* out = (float*)d_out;
    float* ws  = (float*)d_ws;

    const size_t SZ = (size_t)NROWS * M4;   // 2,138,112
    float* lo4 = ws;
    float* h4  = lo4 + SZ;
    float* dlo = h4  + SZ;
    float* dh  = dlo + SZ;
    ushort* xlT = (ushort*)(dh + SZ);        // SZ ushorts
    ushort* xhT = xlT + SZ;                  // SZ ushorts

    dim3 blk(256);

    dwt_fused3<<<NROWS, blk, 0, stream>>>(x, lo4, h4, xlT, xhT);
    einsum_v5<<<1152, blk, 0, stream>>>(xlT, xhT, w1, w2, dlo, dh);
    idwt_delta3<<<NROWS, blk, 0, stream>>>(dlo, dh, lo4, h4, x, out);
}

// Round 8
// 202.280 us; speedup vs baseline: 2.3663x; 1.0523x over previous
//
#include <hip/hip_runtime.h>

// WaveConv1d on MI355X — round 19: einsum_v12 (k-tile 128, clean H3 retest).
//   out = x + idwt(E1(lo4)-lo4, E2(h4)-h4, 0, 0, 0)
// r18: consolidation won (245->213us). einsum back at v5's 113.6us.
// Re-audit: H3 (request size / DRAM page efficiency) was never cleanly tested
// (v9 strangled concurrency; v11 poisoned by serial tail blocks). v5's real
// wave requests are 256B (x) and 4-of-16B strided (w) -> ~30% DRAM page
// efficiency = the observed 2.0 TB/s. v12 = v5 skeleton (same dbuf, same
// __syncthreads, same plain stores, 4-i chunks) with k-tile 128:
//   x staged as 4x 1024B contiguous wave-requests (dwordx4/lane)
//   w staged as 4x  512B contiguous wave-requests (dwordx2/lane, 8B-aligned)
//   compute: 1x ds_read_b128 (x) + 4x ds_read_b64 (w) per ii - conflict-free.
// Tail k=[458,522): 128 blocks running the verbatim v5 path (width 64) in the
// same dispatch; overlap k=[458,512) is written bitwise-identically (same
// i-order, same inputs, plain stores) - benign.
// Grid 640 = 512 main (bid%8 = (kt2,e) pins 64 oq-siblings' x-quarter to one
// XCD) + 128 tail.

#define NROWS 4096          // B*C
#define MODES 522

#define M1 4101
#define M2 2056
#define M3 1033
#define M4 522

typedef unsigned int  uint;
typedef unsigned short ushort;

__constant__ float c_dlo[12] = {
  -0.00107730108499558f,  0.004777257511010651f,  0.0005538422009938016f,
  -0.031582039318031156f, 0.02752286553001629f,   0.09750160558707936f,
  -0.12976686756709563f,  -0.22626469396516913f,  0.3152503517092432f,
   0.7511339080215775f,   0.4946238903983854f,    0.11154074335008017f };
__constant__ float c_dhi[12] = {
  -0.11154074335008017f,  0.4946238903983854f,   -0.7511339080215775f,
   0.3152503517092432f,   0.22626469396516913f,  -0.12976686756709563f,
  -0.09750160558707936f,  0.02752286553001629f,   0.031582039318031156f,
   0.0005538422009938016f,-0.004777257511010651f, -0.00107730108499558f };
// Analysis (time-reversed) filters
__constant__ float c_alo[12] = {
   0.11154074335008017f,  0.4946238903983854f,    0.7511339080215775f,
   0.3152503517092432f,  -0.22626469396516913f,  -0.12976686756709563f,
   0.09750160558707936f,  0.02752286553001629f,  -0.031582039318031156f,
   0.0005538422009938016f, 0.004777257511010651f, -0.00107730108499558f };
__constant__ float c_ahi[12] = {
  -0.00107730108499558f, -0.004777257511010651f,  0.0005538422009938016f,
   0.031582039318031156f, 0.02752286553001629f,  -0.09750160558707936f,
  -0.12976686756709563f,  0.22626469396516913f,   0.3152503517092432f,
  -0.7511339080215775f,   0.4946238903983854f,   -0.11154074335008017f };

__device__ __forceinline__ ushort f2bf(float f) {
    uint b = __float_as_uint(f);
    uint r = (b + 0x7fffu + ((b >> 16) & 1u)) >> 16;
    return (ushort)r;
}

// One lo-only analysis level LDS->LDS, PAIR-vectorized: thread computes
// outputs (j0, j0+1) from 7 float2 LDS reads (window src[2j0-10 .. 2j0+3]).
__device__ __forceinline__
void dwt_lo_pairs(const float* __restrict__ src, int n, int m,
                  float* __restrict__ dst, int tid)
{
    int jhi = (n - 2) >> 1;
    int npairs = (m + 1) >> 1;
    for (int jp = tid; jp < npairs; jp += 256) {
        int j0 = 2 * jp;
        if (j0 >= 6 && j0 + 1 <= jhi) {
            const float2* s2 = (const float2*)(src + 2 * j0 - 10);
            float2 p0 = s2[0], p1 = s2[1], p2 = s2[2], p3 = s2[3],
                   p4 = s2[4], p5 = s2[5], p6 = s2[6];
            float a0 =
                p0.x*c_alo[0] + p0.y*c_alo[1] + p1.x*c_alo[2] + p1.y*c_alo[3] +
                p2.x*c_alo[4] + p2.y*c_alo[5] + p3.x*c_alo[6] + p3.y*c_alo[7] +
                p4.x*c_alo[8] + p4.y*c_alo[9] + p5.x*c_alo[10]+ p5.y*c_alo[11];
            float a1 =
                p1.x*c_alo[0] + p1.y*c_alo[1] + p2.x*c_alo[2] + p2.y*c_alo[3] +
                p3.x*c_alo[4] + p3.y*c_alo[5] + p4.x*c_alo[6] + p4.y*c_alo[7] +
                p5.x*c_alo[8] + p5.y*c_alo[9] + p6.x*c_alo[10]+ p6.y*c_alo[11];
            *(float2*)&dst[j0] = make_float2(a0, a1);
        } else {
#pragma unroll
            for (int q = 0; q < 2; ++q) {
                int j = j0 + q;
                if (j < m) {
                    int base = 2 * j - 10;
                    float a = 0.f;
#pragma unroll
                    for (int t = 0; t < 12; ++t) {
                        int u = base + t;
                        u = (u < 0) ? (-1 - u) : u;
                        u = (u >= n) ? (2 * n - 1 - u) : u;
                        a += src[u] * c_alo[t];
                    }
                    dst[j] = a;
                }
            }
        }
    }
}

// Fused forward DWT, lo-chain only: x -> (lo4, h4) fp32 AND bf16 xT
// [c][g4][k][b4] scattered stores. One block per row; row = b*256 + c.
__global__ __launch_bounds__(256)
void dwt_fused3(const float* __restrict__ x,
                float* __restrict__ lo4g, float* __restrict__ h4g,
                ushort* __restrict__ xlT, ushort* __restrict__ xhT)
{
    __shared__ float X[8192];
    __shared__ float LA[4104];
    int row = blockIdx.x, tid = threadIdx.x;

    const float4* xr = (const float4*)(x + (size_t)row * 8192);
    float4* Xv = (float4*)X;
#pragma unroll
    for (int i = 0; i < 8; ++i) Xv[tid + 256 * i] = xr[tid + 256 * i];
    __syncthreads();

    dwt_lo_pairs(X,  8192, M1, LA, tid);
    __syncthreads();
    dwt_lo_pairs(LA, M1,   M2, X,  tid);
    __syncthreads();
    dwt_lo_pairs(X,  M2,   M3, LA, tid);
    __syncthreads();

    // level 4: dual filter, write lo4/h4 fp32 + xlT/xhT bf16 (scattered)
    float* lo4r = lo4g + (size_t)row * M4;
    float* h4r  = h4g  + (size_t)row * M4;
    int b  = row >> 8, c = row & 255;
    int cg = c * 4 + (b >> 2);
    int b4 = b & 3;
    int jhi = (M3 - 2) >> 1;            // 515
    for (int jp = tid; jp < 261; jp += 256) {
        int j0 = 2 * jp;                // j0+1 = 521 max, always a full pair
        float alo0, ahi0, alo1, ahi1;
        if (j0 >= 6 && j0 + 1 <= jhi) {
            const float2* s2 = (const float2*)(LA + 2 * j0 - 10);
            float2 p0 = s2[0], p1 = s2[1], p2 = s2[2], p3 = s2[3],
                   p4 = s2[4], p5 = s2[5], p6 = s2[6];
            alo0 =
                p0.x*c_alo[0] + p0.y*c_alo[1] + p1.x*c_alo[2] + p1.y*c_alo[3] +
                p2.x*c_alo[4] + p2.y*c_alo[5] + p3.x*c_alo[6] + p3.y*c_alo[7] +
                p4.x*c_alo[8] + p4.y*c_alo[9] + p5.x*c_alo[10]+ p5.y*c_alo[11];
            ahi0 =
                p0.x*c_ahi[0] + p0.y*c_ahi[1] + p1.x*c_ahi[2] + p1.y*c_ahi[3] +
                p2.x*c_ahi[4] + p2.y*c_ahi[5] + p3.x*c_ahi[6] + p3.y*c_ahi[7] +
                p4.x*c_ahi[8] + p4.y*c_ahi[9] + p5.x*c_ahi[10]+ p5.y*c_ahi[11];
            alo1 =
                p1.x*c_alo[0] + p1.y*c_alo[1] + p2.x*c_alo[2] + p2.y*c_alo[3] +
                p3.x*c_alo[4] + p3.y*c_alo[5] + p4.x*c_alo[6] + p4.y*c_alo[7] +
                p5.x*c_alo[8] + p5.y*c_alo[9] + p6.x*c_alo[10]+ p6.y*c_alo[11];
            ahi1 =
                p1.x*c_ahi[0] + p1.y*c_ahi[1] + p2.x*c_ahi[2] + p2.y*c_ahi[3] +
                p3.x*c_ahi[4] + p3.y*c_ahi[5] + p4.x*c_ahi[6] + p4.y*c_ahi[7] +
                p5.x*c_ahi[8] + p5.y*c_ahi[9] + p6.x*c_ahi[10]+ p6.y*c_ahi[11];
        } else {
#pragma unroll
            for (int q = 0; q < 2; ++q) {
                int base = 2 * (j0 + q) - 10;
                float al = 0.f, ah = 0.f;
#pragma unroll
                for (int t = 0; t < 12; ++t) {
                    int u = base + t;
                    u = (u < 0) ? (-1 - u) : u;
                    u = (u >= M3) ? (2 * M3 - 1 - u) : u;
                    float v = LA[u];
                    al += v * c_alo[t]; ah += v * c_ahi[t];
                }
                if (q == 0) { alo0 = al; ahi0 = ah; }
                else        { alo1 = al; ahi1 = ah; }
            }
        }
        *(float2*)&lo4r[j0] = make_float2(alo0, alo1);
        *(float2*)&h4r[j0]  = make_float2(ahi0, ahi1);
        size_t xi = ((size_t)cg * MODES + j0) * 4 + b4;
        xlT[xi]     = f2bf(alo0);
        xlT[xi + 4] = f2bf(alo1);
        xhT[xi]     = f2bf(ahi0);
        xhT[xi + 4] = f2bf(ahi1);
    }
}

// One synthesis (lo-only) level LDS->LDS, pair-vectorized.
__device__ __forceinline__
void ilvl_lo(const float* __restrict__ S, float* __restrict__ D,
             int L, int tid)
{
    int npairs = (L + 1) >> 1;
    for (int tp = tid; tp < npairs; tp += 256) {
        int jj = 2 * tp;
        const float2* s2 = (const float2*)(S + jj);
        float2 q0 = s2[0], q1 = s2[1], q2 = s2[2];
        float e0 = q0.x*c_dlo[1] + q0.y*c_dlo[3] + q1.x*c_dlo[5]
                 + q1.y*c_dlo[7] + q2.x*c_dlo[9] + q2.y*c_dlo[11];
        float od0= q0.x*c_dlo[0] + q0.y*c_dlo[2] + q1.x*c_dlo[4]
                 + q1.y*c_dlo[6] + q2.x*c_dlo[8] + q2.y*c_dlo[10];
        if (jj + 1 < L) {
            float2 q3 = s2[3];
            float e1 = q0.y*c_dlo[1] + q1.x*c_dlo[3] + q1.y*c_dlo[5]
                     + q2.x*c_dlo[7] + q2.y*c_dlo[9] + q3.x*c_dlo[11];
            float od1= q0.y*c_dlo[0] + q1.x*c_dlo[2] + q1.y*c_dlo[4]
                     + q2.x*c_dlo[6] + q2.y*c_dlo[8] + q3.x*c_dlo[10];
            *(float4*)&D[2*jj] = make_float4(e0, od0, e1, od1);
        } else {
            D[2*jj] = e0; D[2*jj+1] = od0;
        }
    }
}

// Delta-IDWT: A = dlo-lo4, Hs = dh-h4; lvl4 full -> lvl3,2,1 lo-only -> +x.
__global__ __launch_bounds__(256)
void idwt_delta3(const float* __restrict__ dlo, const float* __restrict__ dh,
                 const float* __restrict__ lo4, const float* __restrict__ h4,
                 const float* __restrict__ x,   float* __restrict__ out)
{
    __shared__ float A[2056];
    __shared__ float B[4104];
    __shared__ float Hs[528];
    int row = blockIdx.x, tid = threadIdx.x;

    {
        const float2* dl2 = (const float2*)(dlo + (size_t)row * M4);
        const float2* lo2 = (const float2*)(lo4 + (size_t)row * M4);
        const float2* dh2 = (const float2*)(dh  + (size_t)row * M4);
        const float2* h42 = (const float2*)(h4  + (size_t)row * M4);
        for (int tp = tid; tp < 261; tp += 256) {
            float2 a = dl2[tp], bvl = lo2[tp];
            float2 hdd = dh2[tp], hb = h42[tp];
            *(float2*)&A[2*tp]  = make_float2(a.x - bvl.x, a.y - bvl.y);
            *(float2*)&Hs[2*tp] = make_float2(hdd.x - hb.x, hdd.y - hb.y);
        }
    }
    __syncthreads();

    // level 4: dual input (A, Hs), L = M4-5 = 517
    {
        const int L = M4 - 5;
        int npairs = (L + 1) >> 1;   // 259
        for (int tp = tid; tp < npairs; tp += 256) {
            int jj = 2 * tp;
            const float2* a2 = (const float2*)(A + jj);
            const float2* h2 = (const float2*)(Hs + jj);
            float2 a0 = a2[0], a1 = a2[1], aq2 = a2[2];
            float2 h0 = h2[0], h1 = h2[1], hq2 = h2[2];
            float e0 = a0.x*c_dlo[1] + a0.y*c_dlo[3] + a1.x*c_dlo[5]
                     + a1.y*c_dlo[7] + aq2.x*c_dlo[9] + aq2.y*c_dlo[11]
                     + h0.x*c_dhi[1] + h0.y*c_dhi[3] + h1.x*c_dhi[5]
                     + h1.y*c_dhi[7] + hq2.x*c_dhi[9] + hq2.y*c_dhi[11];
            float od0= a0.x*c_dlo[0] + a0.y*c_dlo[2] + a1.x*c_dlo[4]
                     + a1.y*c_dlo[6] + aq2.x*c_dlo[8] + aq2.y*c_dlo[10]
                     + h0.x*c_dhi[0] + h0.y*c_dhi[2] + h1.x*c_dhi[4]
                     + h1.y*c_dhi[6] + hq2.x*c_dhi[8] + hq2.y*c_dhi[10];
            if (jj + 1 < L) {
                float2 a3 = a2[3], h3 = h2[3];
                float e1 = a0.y*c_dlo[1] + a1.x*c_dlo[3] + a1.y*c_dlo[5]
                         + aq2.x*c_dlo[7] + aq2.y*c_dlo[9] + a3.x*c_dlo[11]
                         + h0.y*c_dhi[1] + h1.x*c_dhi[3] + h1.y*c_dhi[5]
                         + hq2.x*c_dhi[7] + hq2.y*c_dhi[9] + h3.x*c_dhi[11];
                float od1= a0.y*c_dlo[0] + a1.x*c_dlo[2] + a1.y*c_dlo[4]
                         + aq2.x*c_dlo[6] + aq2.y*c_dlo[8] + a3.x*c_dlo[10]
                         + h0.y*c_dhi[0] + h1.x*c_dhi[2] + h1.y*c_dhi[4]
                         + hq2.x*c_dhi[6] + hq2.y*c_dhi[8] + h3.x*c_dhi[10];
                *(float4*)&B[2*jj] = make_float4(e0, od0, e1, od1);
            } else {
                B[2*jj] = e0; B[2*jj+1] = od0;
            }
        }
    }
    __syncthreads();

    ilvl_lo(B, A, M3 - 5, tid);      // -> A[0..2055]
    __syncthreads();
    ilvl_lo(A, B, M2 - 5, tid);      // -> B[0..4101]
    __syncthreads();

    // final level: L = M1-5 = 4096 (even -> always full pairs), fused +x.
    {
        const float4* x4 = (const float4*)(x + (size_t)row * 8192);
        float4* o4 = (float4*)(out + (size_t)row * 8192);
        for (int tp = tid; tp < 2048; tp += 256) {
            int jj = 2 * tp;
            const float2* s2 = (const float2*)(B + jj);
            float2 q0 = s2[0], q1 = s2[1], q2 = s2[2], q3 = s2[3];
            float e0 = q0.x*c_dlo[1] + q0.y*c_dlo[3] + q1.x*c_dlo[5]
                     + q1.y*c_dlo[7] + q2.x*c_dlo[9] + q2.y*c_dlo[11];
            float od0= q0.x*c_dlo[0] + q0.y*c_dlo[2] + q1.x*c_dlo[4]
                     + q1.y*c_dlo[6] + q2.x*c_dlo[8] + q2.y*c_dlo[10];
            float e1 = q0.y*c_dlo[1] + q1.x*c_dlo[3] + q1.y*c_dlo[5]
                     + q2.x*c_dlo[7] + q2.y*c_dlo[9] + q3.x*c_dlo[11];
            float od1= q0.y*c_dlo[0] + q1.x*c_dlo[2] + q1.y*c_dlo[4]
                     + q2.x*c_dlo[6] + q2.y*c_dlo[8] + q3.x*c_dlo[10];
            float4 xv = x4[tp];
            o4[tp] = make_float4(xv.x + e0, xv.y + od0, xv.z + e1, xv.w + od1);
        }
    }
}

// Dual einsum v12: k-tile 128 main blocks + verbatim-v5 tail blocks.
// dlo[b,o,k] = sum_i x[b,i,k]*w[i,o,k]   (subtract happens in idwt_delta3)
// Main (bid<512): kt2=bid&3, e=(bid>>2)&1, oq=bid>>3; kbase=128*kt2.
//   Per chunk (4 i) per wave: x = 4x dwordx4 wave-req (1024B contiguous),
//   w = 4x dwordx2 wave-req (512B contiguous, 8B-aligned). Compute per ii:
//   1 ds_read_b128 (x: k-pair x 4b) + 4 ds_read_b64 (w per j) + 32 FMA.
//   acc[4b][4j][2k]; plain float2 stores.
// Tail (bid>=512): tb=bid-512, e=tb>>6, oq=tb&63, kbase=458, width 64 —
//   verbatim v5 code. Overlap k=[458,512) with main kt2=3 is written
//   bitwise-identically (same i-order, same inputs) — benign.
__global__ __launch_bounds__(256)
void einsum_v12(const ushort* __restrict__ xlT, const ushort* __restrict__ xhT,
                const float* __restrict__ w1,   const float* __restrict__ w2,
                float* __restrict__ dlo, float* __restrict__ dh)
{
    __shared__ ushort Xb[2][8192];   // main: [buf][((il*4+g)*128+k)*4+b] 32 KB
    __shared__ float  Wb[2][2048];   // main: [buf][(il*4+j)*128+k]       16 KB

    int bid  = blockIdx.x;
    int lane = threadIdx.x & 63;
    int wv   = threadIdx.x >> 6;
    int t    = threadIdx.x;

    if (bid < 512) {
        // ================= main path: k-width 128 =================
        int kt2 = bid & 3;
        int e   = (bid >> 2) & 1;
        int oq  = bid >> 3;
        const ushort* xT = e ? xhT : xlT;
        const float*  w  = e ? w2  : w1;
        float* outp      = e ? dh  : dlo;
        int o     = oq * 4;
        int kbase = kt2 * 128;

        // staging bases: wave wv stages il=wv (i = ch*4+wv)
        // x seg (il=wv, g): 1024B contiguous; lane reads 16B at +lane*16
        const ushort* xg0 = xT + (((size_t)wv * 4 + 0) * MODES + kbase) * 4 + lane * 8;
        const ushort* xg1 = xT + (((size_t)wv * 4 + 1) * MODES + kbase) * 4 + lane * 8;
        const ushort* xg2 = xT + (((size_t)wv * 4 + 2) * MODES + kbase) * 4 + lane * 8;
        const ushort* xg3 = xT + (((size_t)wv * 4 + 3) * MODES + kbase) * 4 + lane * 8;
        const size_t XCH = (size_t)4 * 4 * MODES * 4;   // ushorts per chunk (4 i)
        // w row (il=wv, j): 512B contiguous; lane reads 8B at +lane*2 floats
        const float* wj0 = w + ((size_t)wv * 256 + o + 0) * MODES + kbase + lane * 2;
        const float* wj1 = w + ((size_t)wv * 256 + o + 1) * MODES + kbase + lane * 2;
        const float* wj2 = w + ((size_t)wv * 256 + o + 2) * MODES + kbase + lane * 2;
        const float* wj3 = w + ((size_t)wv * 256 + o + 3) * MODES + kbase + lane * 2;
        const size_t WCH = (size_t)4 * 256 * MODES;     // floats per chunk

        float acc[4][4][2];
#pragma unroll
        for (int q = 0; q < 4; ++q)
#pragma unroll
            for (int j = 0; j < 4; ++j) { acc[q][j][0] = 0.f; acc[q][j][1] = 0.f; }

        uint4  xv0, xv1, xv2, xv3;
        float2 wv0, wv1, wv2, wv3;

#define LOADCH(CH) do {                                                       \
        size_t xo_ = (size_t)(CH) * XCH;                                      \
        xv0 = *(const uint4*)(xg0 + xo_); xv1 = *(const uint4*)(xg1 + xo_);   \
        xv2 = *(const uint4*)(xg2 + xo_); xv3 = *(const uint4*)(xg3 + xo_);   \
        size_t wo_ = (size_t)(CH) * WCH;                                      \
        wv0 = *(const float2*)(wj0 + wo_); wv1 = *(const float2*)(wj1 + wo_); \
        wv2 = *(const float2*)(wj2 + wo_); wv3 = *(const float2*)(wj3 + wo_); \
    } while (0)

#define WRITECH(NB) do {                                                      \
        *(uint4*)&Xb[NB][(wv * 4 + 0) * 512 + lane * 8] = xv0;                \
        *(uint4*)&Xb[NB][(wv * 4 + 1) * 512 + lane * 8] = xv1;                \
        *(uint4*)&Xb[NB][(wv * 4 + 2) * 512 + lane * 8] = xv2;                \
        *(uint4*)&Xb[NB][(wv * 4 + 3) * 512 + lane * 8] = xv3;                \
        *(float2*)&Wb[NB][(wv * 4 + 0) * 128 + lane * 2] = wv0;               \
        *(float2*)&Wb[NB][(wv * 4 + 1) * 128 + lane * 2] = wv1;               \
        *(float2*)&Wb[NB][(wv * 4 + 2) * 128 + lane * 2] = wv2;               \
        *(float2*)&Wb[NB][(wv * 4 + 3) * 128 + lane * 2] = wv3;               \
    } while (0)

        // prologue: stage chunk 0
        LOADCH(0);
        WRITECH(0);
        __syncthreads();

        for (int ch = 0; ch < 64; ++ch) {
            int cur = ch & 1, nb = cur ^ 1;
            if (ch < 63) LOADCH(ch + 1);

            // compute chunk ch from buf cur
#pragma unroll
            for (int ii = 0; ii < 4; ++ii) {
                uint4 xq = *(const uint4*)&Xb[cur][((ii * 4 + wv) * 128 + 2 * lane) * 4];
                // k0: b0..b3 from xq.x, xq.y; k1: from xq.z, xq.w
                float x00 = __uint_as_float(xq.x << 16);
                float x01 = __uint_as_float(xq.x & 0xffff0000u);
                float x02 = __uint_as_float(xq.y << 16);
                float x03 = __uint_as_float(xq.y & 0xffff0000u);
                float x10 = __uint_as_float(xq.z << 16);
                float x11 = __uint_as_float(xq.z & 0xffff0000u);
                float x12 = __uint_as_float(xq.w << 16);
                float x13 = __uint_as_float(xq.w & 0xffff0000u);
                float2 wq0 = *(const float2*)&Wb[cur][(ii * 4 + 0) * 128 + 2 * lane];
                float2 wq1 = *(const float2*)&Wb[cur][(ii * 4 + 1) * 128 + 2 * lane];
                float2 wq2 = *(const float2*)&Wb[cur][(ii * 4 + 2) * 128 + 2 * lane];
                float2 wq3 = *(const float2*)&Wb[cur][(ii * 4 + 3) * 128 + 2 * lane];
                acc[0][0][0] += x00 * wq0.x; acc[0][0][1] += x10 * wq0.y;
                acc[0][1][0] += x00 * wq1.x; acc[0][1][1] += x10 * wq1.y;
                acc[0][2][0] += x00 * wq2.x; acc[0][2][1] += x10 * wq2.y;
                acc[0][3][0] += x00 * wq3.x; acc[0][3][1] += x10 * wq3.y;
                acc[1][0][0] += x01 * wq0.x; acc[1][0][1] += x11 * wq0.y;
                acc[1][1][0] += x01 * wq1.x; acc[1][1][1] += x11 * wq1.y;
                acc[1][2][0] += x01 * wq2.x; acc[1][2][1] += x11 * wq2.y;
                acc[1][3][0] += x01 * wq3.x; acc[1][3][1] += x11 * wq3.y;
                acc[2][0][0] += x02 * wq0.x; acc[2][0][1] += x12 * wq0.y;
                acc[2][1][0] += x02 * wq1.x; acc[2][1][1] += x12 * wq1.y;
                acc[2][2][0] += x02 * wq2.x; acc[2][2][1] += x12 * wq2.y;
                acc[2][3][0] += x02 * wq3.x; acc[2][3][1] += x12 * wq3.y;
                acc[3][0][0] += x03 * wq0.x; acc[3][0][1] += x13 * wq0.y;
                acc[3][1][0] += x03 * wq1.x; acc[3][1][1] += x13 * wq1.y;
                acc[3][2][0] += x03 * wq2.x; acc[3][2][1] += x13 * wq2.y;
                acc[3][3][0] += x03 * wq3.x; acc[3][3][1] += x13 * wq3.y;
            }

            if (ch < 63) WRITECH(nb);
            __syncthreads();
        }
#undef LOADCH
#undef WRITECH

        // stores: float2 per (b,j) at k = kbase + 2*lane
#pragma unroll
        for (int q = 0; q < 4; ++q) {
            int b = 4 * wv + q;
#pragma unroll
            for (int j = 0; j < 4; ++j)
                *(float2*)&outp[((size_t)b * 256 + o + j) * MODES + kbase + 2 * lane]
                    = make_float2(acc[q][j][0], acc[q][j][1]);
        }
    } else {
        // ================= tail path: verbatim v5, kbase=458 =================
        int tb = bid - 512;
        int e  = tb >> 6;
        int oq = tb & 63;
        const ushort* xT = e ? xhT : xlT;
        const float*  w  = e ? w2  : w1;
        float* outp      = e ? dh  : dlo;
        int kbase = MODES - 64;   // 458
        int o     = oq * 4;

        int run = t >> 4, piece = t & 15;
        int il = run >> 2, sub = run & 3;

        const ushort* xrunb = xT + (((size_t)il * 4 + sub) * MODES + kbase) * 4 + piece * 16;
        const size_t xistr = (size_t)4 * MODES * 4;
        const float* wrunb = w + ((size_t)il * 256 + o + sub) * MODES + kbase + piece * 4;
        const size_t wistr = (size_t)256 * MODES;

        float acc[4][4];
#pragma unroll
        for (int q = 0; q < 4; ++q)
#pragma unroll
            for (int j = 0; j < 4; ++j) acc[q][j] = 0.f;

        {
            uint4 v0 = *(const uint4*)(xrunb);
            uint4 v1 = *(const uint4*)(xrunb + 8);
            float f0 = wrunb[0], f1 = wrunb[1], f2 = wrunb[2], f3 = wrunb[3];
            uint4* xd = (uint4*)&Xb[0][t * 16];
            xd[0] = v0; xd[1] = v1;
            float4* wd = (float4*)&Wb[0][t * 4];
            *wd = make_float4(f0, f1, f2, f3);
        }
        __syncthreads();

        for (int ch = 0; ch < 64; ++ch) {
            int cur = ch & 1, nb = cur ^ 1;
            uint4 v0, v1; float f0, f1, f2, f3;
            if (ch < 63) {
                const ushort* xs = xrunb + (size_t)(ch + 1) * 4 * xistr;
                v0 = *(const uint4*)(xs);
                v1 = *(const uint4*)(xs + 8);
                const float* wsv = wrunb + (size_t)(ch + 1) * 4 * wistr;
                f0 = wsv[0]; f1 = wsv[1]; f2 = wsv[2]; f3 = wsv[3];
            }

#pragma unroll
            for (int ii = 0; ii < 4; ++ii) {
                uint2 xp = *(const uint2*)&Xb[cur][(((ii * 4) + wv) * 64 + lane) * 4];
                float x0 = __uint_as_float(xp.x << 16);
                float x1 = __uint_as_float(xp.x & 0xffff0000u);
                float x2 = __uint_as_float(xp.y << 16);
                float x3 = __uint_as_float(xp.y & 0xffff0000u);
                float wr0 = Wb[cur][(ii * 4 + 0) * 64 + lane];
                float wr1 = Wb[cur][(ii * 4 + 1) * 64 + lane];
                float wr2 = Wb[cur][(ii * 4 + 2) * 64 + lane];
                float wr3 = Wb[cur][(ii * 4 + 3) * 64 + lane];
                acc[0][0] += x0 * wr0; acc[0][1] += x0 * wr1;
                acc[0][2] += x0 * wr2; acc[0][3] += x0 * wr3;
                acc[1][0] += x1 * wr0; acc[1][1] += x1 * wr1;
                acc[1][2] += x1 * wr2; acc[1][3] += x1 * wr3;
                acc[2][0] += x2 * wr0; acc[2][1] += x2 * wr1;
                acc[2][2] += x2 * wr2; acc[2][3] += x2 * wr3;
                acc[3][0] += x3 * wr0; acc[3][1] += x3 * wr1;
                acc[3][2] += x3 * wr2; acc[3][3] += x3 * wr3;
            }

            if (ch < 63) {
                uint4* xd = (uint4*)&Xb[nb][t * 16];
                xd[0] = v0; xd[1] = v1;
                float4* wd = (float4*)&Wb[nb][t * 4];
                *wd = make_float4(f0, f1, f2, f3);
            }
            __syncthreads();
        }

#pragma unroll
        for (int q = 0; q < 4; ++q) {
            int b = 4 * wv + q;
#pragma unroll
            for (int j = 0; j < 4; ++j)
                outp[((size_t)b * 256 + o + j) * MODES + kbase + lane] = acc[q][j];
        }
    }
}

extern "C" void kernel_launch(void* const* d_in, const int* in_sizes, int n_in,
                              void* d_out, int out_size, void* d_ws, size_t ws_size,
                              hipStream_t stream)
{
    const float* x  = (const float*)d_in[0];
    const float* w1 = (const float*)d_in[1];
    const float* w2 = (const float*)d_in[2];
    float* out = (float*)d_out;
    float* ws  = (float*)d_ws;

    const size_t SZ = (size_t)NROWS * M4;   // 2,138,112
    float* lo4 = ws;
    float* h4  = lo4 + SZ;
    float* dlo = h4  + SZ;
    float* dh  = dlo + SZ;
    ushort* xlT = (ushort*)(dh + SZ);        // SZ ushorts
    ushort* xhT = xlT + SZ;                  // SZ ushorts

    dim3 blk(256);

    dwt_fused3<<<NROWS, blk, 0, stream>>>(x, lo4, h4, xlT, xhT);
    einsum_v12<<<640, blk, 0, stream>>>(xlT, xhT, w1, w2, dlo, dh);
    idwt_delta3<<<NROWS, blk, 0, stream>>>(dlo, dh, lo4, h4, x, out);
}